// Round 4
// baseline (144.731 us; speedup 1.0000x reference)
//
#include <hip/hip_runtime.h>
#include <hip/hip_bf16.h>

// HSA prefill R19 (2nd resubmit; R2/R3 benches were GPU-broker timeouts —
// no data, kernel never ran). R19 = R18 fused into ONE kernel
// (pack + device barrier + main).
// Why: rocprof top-5 is 100% harness poison-fill (~42us) -> hsa_main (~40us)
// is invisible; 2 rounds of theory were unfalsifiable. Fusing makes the hot
// dispatch ~45us -> lands in top-5 -> real counters next round. Side wins:
// one launch removed, pack runs on 512x512 threads (2x parallelism).
// Barrier safety: __launch_bounds__(512,4) pins <=128 VGPR and LDS=68KB ->
// exactly 2 blocks/CU -> grid 512 == residency capacity -> no deadlock.
// Coherence: producers' stores drain at __syncthreads (compiler vmcnt(0)),
// thread0 __threadfence() (agent: L2 writeback) before release-arrival;
// acquire-spin + __threadfence() (invalidate) before consuming other XCDs'
// packed data. Epoch counters are __device__ globals: not in the poisoned
// workspace, monotonic -> correct across warmup/graph-replay iterations.
// Phase-2 body is R18 verbatim (XCD-h swizzle, dual-bank V streaming,
// interleaved scores, qf in LDS, dual P slices, tree-combine epilogue).

namespace {

constexpr int kLq = 256, kHQ = 32, kH = 2, kG = 16, kD = 128, kS = 16;
constexpr int kNB = 64;                    // Lkv/BS: distinct blocks per head
constexpr float kScaleLog2e = 0.08838834764831845f * 1.4426950408889634f;

constexpr int kKPackN = kH * kNB * 16 * 64;  // uint4 elems per array (2 MB)
constexpr int kPStr   = 72;                  // P row stride (shorts)
constexpr int kSStr   = 136;                 // pack LDS row stride (shorts)
constexpr int kGrid   = 512;                 // grid size == residency capacity

// LDS layout (bytes):
//   phase 1:          S_s pack staging [0, 8704)
//   phase 2:
//   [0, 32768)        qf slices:  wave*4096 + st*1024 + lane*16  (epi reuse)
//   [32768, 69632)    P slices:   wave*4608 + blk*2304 + (n*72+u)*2
constexpr int kQOff = 0;
constexpr int kPOff = 32768;

typedef short s16x8 __attribute__((ext_vector_type(8)));
typedef float f32x4 __attribute__((ext_vector_type(4)));

union U32BF2 { unsigned int u; __hip_bfloat162 h; };
union FragU  { uint4 u; s16x8 v; };

static __device__ inline unsigned int pk_bf16(float a, float b) {
    U32BF2 z; z.h = __float22bfloat162_rn(make_float2(a, b));
    return z.u;
}

// grid-barrier state (module globals: zero-initialized once at load, never
// poisoned by the harness; monotonic across iterations).
__device__ int g_arrive = 0;
__device__ int g_epoch  = 0;

__global__ __launch_bounds__(512, 4)
void hsa_fused(const float* __restrict__ q, const float* __restrict__ k,
               const float* __restrict__ v, const float* __restrict__ w,
               const int* __restrict__ bidx, uint4* __restrict__ kp,
               uint4* __restrict__ vp, float* __restrict__ out)
{
    __shared__ __align__(16) unsigned char smem[69632];   // 68 KB

    const int bid  = blockIdx.x;                 // 0..511
    const int tid  = threadIdx.x;
    const int wave = tid >> 6;                   // 0..7
    const int lane = tid & 63;
    const int n    = lane & 15;
    const int quad = lane >> 4;

    // ================= phase 1: pack chunk 'bid' (512 threads) =============
    // K_packed idx = ((h*64+blk)*16 + t*4+st)*64 + lane (lane = quad*16+n)
    //   holds K[u = blk*64 + t*16 + n][h][d = st*32 + quad*8 + j]
    // V_packed idx = ((h*64+blk)*16 + dt*2+st)*64 + lane
    //   holds V[u = blk*64 + st*32 + quad*8 + j][h][d = dt*16 + n]
    {
        unsigned short* S_s = (unsigned short*)smem;   // 32 x kSStr shorts
        const int isV  = bid & 1;
        const int half = (bid >> 1) & 1;
        const int blk  = (bid >> 2) & 63;
        const int hh   = bid >> 8;
        const int wv8  = tid >> 6;                     // 0..7

        {   // coalesced load 32 rows x 128 fp32 -> bf16 LDS (2 iters @512 thr)
            const float* src = (isV ? v : k) +
                ((size_t)(blk * 64 + half * 32) * kH + hh) * kD;
            const int r0 = tid >> 5, c4 = (tid & 31) << 2;
            #pragma unroll
            for (int p = 0; p < 2; ++p) {
                const int r = p * 16 + r0;
                const f32x4 f = __builtin_nontemporal_load(
                    (const f32x4*)(src + (size_t)r * (kH * kD) + c4));
                *(unsigned int*)&S_s[r * kSStr + c4]     = pk_bf16(f[0], f[1]);
                *(unsigned int*)&S_s[r * kSStr + c4 + 2] = pk_bf16(f[2], f[3]);
            }
        }
        __syncthreads();

        const size_t obase = (size_t)(hh * 64 + blk) * 16 * 64;
        if (!isV) {
            const int t_loc = wv8 >> 2, st = wv8 & 3;
            const int c     = (2 * half + t_loc) * 4 + st;
            const int u_loc = t_loc * 16 + n;
            kp[obase + (size_t)c * 64 + lane] =
                *(const uint4*)&S_s[u_loc * kSStr + st * 32 + quad * 8];
        } else {
            const int dt = wv8;
            const int c  = dt * 2 + half;
            const int d  = dt * 16 + n;
            unsigned short s[8];
            #pragma unroll
            for (int j = 0; j < 8; ++j) s[j] = S_s[(quad * 8 + j) * kSStr + d];
            uint4 val;
            val.x = s[0] | ((unsigned)s[1] << 16);
            val.y = s[2] | ((unsigned)s[3] << 16);
            val.z = s[4] | ((unsigned)s[5] << 16);
            val.w = s[6] | ((unsigned)s[7] << 16);
            vp[obase + (size_t)c * 64 + lane] = val;
        }
    }

    // ================= grid barrier (all 512 wgs co-resident) ==============
    __syncthreads();   // compiler drains vmcnt before s_barrier -> stores in L2
    if (tid == 0) {
        __threadfence();   // agent fence: write back this XCD's L2
        const int a  = __hip_atomic_fetch_add(&g_arrive, 1, __ATOMIC_ACQ_REL,
                                              __HIP_MEMORY_SCOPE_AGENT);
        const int ep = a / kGrid;
        if ((a % kGrid) == kGrid - 1)
            __hip_atomic_fetch_add(&g_epoch, 1, __ATOMIC_ACQ_REL,
                                   __HIP_MEMORY_SCOPE_AGENT);
        while (__hip_atomic_load(&g_epoch, __ATOMIC_ACQUIRE,
                                 __HIP_MEMORY_SCOPE_AGENT) <= ep)
            __builtin_amdgcn_s_sleep(2);
        __threadfence();   // invalidate before reading other XCDs' packs
    }
    __syncthreads();

    // ================= phase 2: main (R18 body) =============================
    // XCD-aware remap: bid round-robins over 8 XCDs; give XCDs 0-3 h=0 and
    // XCDs 4-7 h=1 so each XCD's L2 holds one head's kp+vp (2 MB).
    const int xcd = bid & 7;
    const int h   = xcd >> 2;
    const int l   = (bid >> 3) * 4 + (xcd & 3);

    // ---- Q B-frags -> per-wave LDS slice (frees 16 VGPR); nt loads ----
    unsigned char* qlds = smem + kQOff + wave * 4096 + lane * 16;
    {
        const float* qb = q + ((size_t)l * kHQ + h * kG + n) * kD + quad * 8;
        #pragma unroll
        for (int st = 0; st < 4; ++st) {
            const f32x4 f0 = __builtin_nontemporal_load((const f32x4*)(qb + st * 32));
            const f32x4 f1 = __builtin_nontemporal_load((const f32x4*)(qb + st * 32 + 4));
            uint4 z;
            z.x = pk_bf16(f0[0], f0[1]); z.y = pk_bf16(f0[2], f0[3]);
            z.z = pk_bf16(f1[0], f1[1]); z.w = pk_bf16(f1[2], f1[3]);
            *(uint4*)(qlds + st * 1024) = z;
        }
    }

    // this wave's 2 s-blocks A,B: s = wave*2 + {0,1}
    int   baseA, baseB;
    float wvalA, wvalB;
    {
        const int sA = wave * 2, sB = wave * 2 + 1;
        const int biA = bidx[(size_t)(l * kH + h) * kS + sA];
        const int biB = bidx[(size_t)(l * kH + h) * kS + sB];
        wvalA = (biA < 0) ? 0.f : w[((size_t)l * kHQ + h * kG + n) * kS + sA];
        wvalB = (biB < 0) ? 0.f : w[((size_t)l * kHQ + h * kG + n) * kS + sB];
        baseA = (h * kNB + max(biA, 0)) * 1024;
        baseB = (h * kNB + max(biB, 0)) * 1024;
    }

    unsigned short* PA = (unsigned short*)(smem + kPOff + wave * 4608);
    unsigned short* PB = PA + kG * kPStr;

    // prologue: kA <- A-K-g0, kB <- B-K-g0, vrA <- A-V-g0, vrB <- A-V-g1
    FragU kA[4], kB[4], vrA[4], vrB[4];
    #pragma unroll
    for (int st = 0; st < 4; ++st) kA[st].u = kp[baseA + st * 64 + lane];
    #pragma unroll
    for (int st = 0; st < 4; ++st) kB[st].u = kp[baseB + st * 64 + lane];
    #pragma unroll
    for (int i = 0; i < 4; ++i)    vrA[i].u = vp[baseA + i * 64 + lane];
    #pragma unroll
    for (int i = 0; i < 4; ++i)    vrB[i].u = vp[baseA + (4 + i) * 64 + lane];
    __builtin_amdgcn_sched_barrier(0);

    f32x4 oacc[8];
    #pragma unroll
    for (int dt = 0; dt < 8; ++dt) oacc[dt] = (f32x4){0.f, 0.f, 0.f, 0.f};

    // ---- interleaved scores: A-t, B-t alternate ----
    float partA = 0.f, partB = 0.f;
    #pragma unroll
    for (int t = 0; t < 4; ++t) {
        {   // A group t
            f32x4 sc = {0.f, 0.f, 0.f, 0.f};
            #pragma unroll
            for (int st = 0; st < 4; ++st) {
                const s16x8 aq = *(const s16x8*)(qlds + st * 1024);
                sc = __builtin_amdgcn_mfma_f32_16x16x32_bf16(kA[st].v, aq, sc, 0, 0, 0);
            }
            if (t < 3) {
                #pragma unroll
                for (int st = 0; st < 4; ++st)
                    kA[st].u = kp[baseA + ((t + 1) * 4 + st) * 64 + lane];
            }
            __builtin_amdgcn_sched_barrier(0);
            #pragma unroll
            for (int r = 0; r < 4; ++r) {
                sc[r] = exp2f(sc[r] * kScaleLog2e);
                partA += sc[r];
            }
            const unsigned long long pq =
                ((unsigned long long)pk_bf16(sc[2], sc[3]) << 32) | pk_bf16(sc[0], sc[1]);
            *(unsigned long long*)&PA[n * kPStr + t * 16 + quad * 4] = pq;
        }
        {   // B group t
            f32x4 sc = {0.f, 0.f, 0.f, 0.f};
            #pragma unroll
            for (int st = 0; st < 4; ++st) {
                const s16x8 aq = *(const s16x8*)(qlds + st * 1024);
                sc = __builtin_amdgcn_mfma_f32_16x16x32_bf16(kB[st].v, aq, sc, 0, 0, 0);
            }
            if (t < 3) {
                #pragma unroll
                for (int st = 0; st < 4; ++st)
                    kB[st].u = kp[baseB + ((t + 1) * 4 + st) * 64 + lane];
            }
            __builtin_amdgcn_sched_barrier(0);
            #pragma unroll
            for (int r = 0; r < 4; ++r) {
                sc[r] = exp2f(sc[r] * kScaleLog2e);
                partB += sc[r];
            }
            const unsigned long long pq =
                ((unsigned long long)pk_bf16(sc[2], sc[3]) << 32) | pk_bf16(sc[0], sc[1]);
            *(unsigned long long*)&PB[n * kPStr + t * 16 + quad * 4] = pq;
        }
    }

    // ---- intra-wave denominators ----
    partA += __shfl_xor(partA, 16);
    partA += __shfl_xor(partA, 32);
    partB += __shfl_xor(partB, 16);
    partB += __shfl_xor(partB, 32);
    const float coefA = wvalA / partA;
    const float coefB = wvalB / partB;

    const f32x4 zero = {0.f, 0.f, 0.f, 0.f};

    // ---- PV(A): banks alternate; refill distance = 2 V-groups ----
    {
        const s16x8 bf0 = *(const s16x8*)&PA[n * kPStr + quad * 8];
        const s16x8 bf1 = *(const s16x8*)&PA[n * kPStr + 32 + quad * 8];

        // vg0: vrA = A-g0 -> d-tiles 0,1 ; refill vrA <- A-g2
        {
            f32x4 p0 = __builtin_amdgcn_mfma_f32_16x16x32_bf16(vrA[0].v, bf0, zero, 0, 0, 0);
            p0       = __builtin_amdgcn_mfma_f32_16x16x32_bf16(vrA[1].v, bf1, p0,   0, 0, 0);
            f32x4 p1 = __builtin_amdgcn_mfma_f32_16x16x32_bf16(vrA[2].v, bf0, zero, 0, 0, 0);
            p1       = __builtin_amdgcn_mfma_f32_16x16x32_bf16(vrA[3].v, bf1, p1,   0, 0, 0);
            #pragma unroll
            for (int i = 0; i < 4; ++i) vrA[i].u = vp[baseA + (8 + i) * 64 + lane];
            __builtin_amdgcn_sched_barrier(0);
            #pragma unroll
            for (int r = 0; r < 4; ++r) {
                oacc[0][r] = fmaf(coefA, p0[r], oacc[0][r]);
                oacc[1][r] = fmaf(coefA, p1[r], oacc[1][r]);
            }
        }
        // vg1: vrB = A-g1 -> d-tiles 2,3 ; refill vrB <- A-g3
        {
            f32x4 p0 = __builtin_amdgcn_mfma_f32_16x16x32_bf16(vrB[0].v, bf0, zero, 0, 0, 0);
            p0       = __builtin_amdgcn_mfma_f32_16x16x32_bf16(vrB[1].v, bf1, p0,   0, 0, 0);
            f32x4 p1 = __builtin_amdgcn_mfma_f32_16x16x32_bf16(vrB[2].v, bf0, zero, 0, 0, 0);
            p1       = __builtin_amdgcn_mfma_f32_16x16x32_bf16(vrB[3].v, bf1, p1,   0, 0, 0);
            #pragma unroll
            for (int i = 0; i < 4; ++i) vrB[i].u = vp[baseA + (12 + i) * 64 + lane];
            __builtin_amdgcn_sched_barrier(0);
            #pragma unroll
            for (int r = 0; r < 4; ++r) {
                oacc[2][r] = fmaf(coefA, p0[r], oacc[2][r]);
                oacc[3][r] = fmaf(coefA, p1[r], oacc[3][r]);
            }
        }
        // vg2: vrA = A-g2 -> d-tiles 4,5 ; refill vrA <- B-g0
        {
            f32x4 p0 = __builtin_amdgcn_mfma_f32_16x16x32_bf16(vrA[0].v, bf0, zero, 0, 0, 0);
            p0       = __builtin_amdgcn_mfma_f32_16x16x32_bf16(vrA[1].v, bf1, p0,   0, 0, 0);
            f32x4 p1 = __builtin_amdgcn_mfma_f32_16x16x32_bf16(vrA[2].v, bf0, zero, 0, 0, 0);
            p1       = __builtin_amdgcn_mfma_f32_16x16x32_bf16(vrA[3].v, bf1, p1,   0, 0, 0);
            #pragma unroll
            for (int i = 0; i < 4; ++i) vrA[i].u = vp[baseB + i * 64 + lane];
            __builtin_amdgcn_sched_barrier(0);
            #pragma unroll
            for (int r = 0; r < 4; ++r) {
                oacc[4][r] = fmaf(coefA, p0[r], oacc[4][r]);
                oacc[5][r] = fmaf(coefA, p1[r], oacc[5][r]);
            }
        }
        // vg3: vrB = A-g3 -> d-tiles 6,7 ; refill vrB <- B-g1
        {
            f32x4 p0 = __builtin_amdgcn_mfma_f32_16x16x32_bf16(vrB[0].v, bf0, zero, 0, 0, 0);
            p0       = __builtin_amdgcn_mfma_f32_16x16x32_bf16(vrB[1].v, bf1, p0,   0, 0, 0);
            f32x4 p1 = __builtin_amdgcn_mfma_f32_16x16x32_bf16(vrB[2].v, bf0, zero, 0, 0, 0);
            p1       = __builtin_amdgcn_mfma_f32_16x16x32_bf16(vrB[3].v, bf1, p1,   0, 0, 0);
            #pragma unroll
            for (int i = 0; i < 4; ++i) vrB[i].u = vp[baseB + (4 + i) * 64 + lane];
            __builtin_amdgcn_sched_barrier(0);
            #pragma unroll
            for (int r = 0; r < 4; ++r) {
                oacc[6][r] = fmaf(coefA, p0[r], oacc[6][r]);
                oacc[7][r] = fmaf(coefA, p1[r], oacc[7][r]);
            }
        }
    }

    // ---- PV(B): same bank rotation on block B ----
    {
        const s16x8 bf0 = *(const s16x8*)&PB[n * kPStr + quad * 8];
        const s16x8 bf1 = *(const s16x8*)&PB[n * kPStr + 32 + quad * 8];

        // vg0: vrA = B-g0 -> d-tiles 0,1 ; refill vrA <- B-g2
        {
            f32x4 p0 = __builtin_amdgcn_mfma_f32_16x16x32_bf16(vrA[0].v, bf0, zero, 0, 0, 0);
            p0       = __builtin_amdgcn_mfma_f32_16x16x32_bf16(vrA[1].v, bf1, p0,   0, 0, 0);
            f32x4 p1 = __builtin_amdgcn_mfma_f32_16x16x32_bf16(vrA[2].v, bf0, zero, 0, 0, 0);
            p1       = __builtin_amdgcn_mfma_f32_16x16x32_bf16(vrA[3].v, bf1, p1,   0, 0, 0);
            #pragma unroll
            for (int i = 0; i < 4; ++i) vrA[i].u = vp[baseB + (8 + i) * 64 + lane];
            __builtin_amdgcn_sched_barrier(0);
            #pragma unroll
            for (int r = 0; r < 4; ++r) {
                oacc[0][r] = fmaf(coefB, p0[r], oacc[0][r]);
                oacc[1][r] = fmaf(coefB, p1[r], oacc[1][r]);
            }
        }
        // vg1: vrB = B-g1 -> d-tiles 2,3 ; refill vrB <- B-g3
        {
            f32x4 p0 = __builtin_amdgcn_mfma_f32_16x16x32_bf16(vrB[0].v, bf0, zero, 0, 0, 0);
            p0       = __builtin_amdgcn_mfma_f32_16x16x32_bf16(vrB[1].v, bf1, p0,   0, 0, 0);
            f32x4 p1 = __builtin_amdgcn_mfma_f32_16x16x32_bf16(vrB[2].v, bf0, zero, 0, 0, 0);
            p1       = __builtin_amdgcn_mfma_f32_16x16x32_bf16(vrB[3].v, bf1, p1,   0, 0, 0);
            #pragma unroll
            for (int i = 0; i < 4; ++i) vrB[i].u = vp[baseB + (12 + i) * 64 + lane];
            __builtin_amdgcn_sched_barrier(0);
            #pragma unroll
            for (int r = 0; r < 4; ++r) {
                oacc[2][r] = fmaf(coefB, p0[r], oacc[2][r]);
                oacc[3][r] = fmaf(coefB, p1[r], oacc[3][r]);
            }
        }
        // vg2: vrA = B-g2 -> d-tiles 4,5 (no refill)
        {
            f32x4 p0 = __builtin_amdgcn_mfma_f32_16x16x32_bf16(vrA[0].v, bf0, zero, 0, 0, 0);
            p0       = __builtin_amdgcn_mfma_f32_16x16x32_bf16(vrA[1].v, bf1, p0,   0, 0, 0);
            f32x4 p1 = __builtin_amdgcn_mfma_f32_16x16x32_bf16(vrA[2].v, bf0, zero, 0, 0, 0);
            p1       = __builtin_amdgcn_mfma_f32_16x16x32_bf16(vrA[3].v, bf1, p1,   0, 0, 0);
            #pragma unroll
            for (int r = 0; r < 4; ++r) {
                oacc[4][r] = fmaf(coefB, p0[r], oacc[4][r]);
                oacc[5][r] = fmaf(coefB, p1[r], oacc[5][r]);
            }
        }
        // vg3: vrB = B-g3 -> d-tiles 6,7 (no refill)
        {
            f32x4 p0 = __builtin_amdgcn_mfma_f32_16x16x32_bf16(vrB[0].v, bf0, zero, 0, 0, 0);
            p0       = __builtin_amdgcn_mfma_f32_16x16x32_bf16(vrB[1].v, bf1, p0,   0, 0, 0);
            f32x4 p1 = __builtin_amdgcn_mfma_f32_16x16x32_bf16(vrB[2].v, bf0, zero, 0, 0, 0);
            p1       = __builtin_amdgcn_mfma_f32_16x16x32_bf16(vrB[3].v, bf1, p1,   0, 0, 0);
            #pragma unroll
            for (int r = 0; r < 4; ++r) {
                oacc[6][r] = fmaf(coefB, p0[r], oacc[6][r]);
                oacc[7][r] = fmaf(coefB, p1[r], oacc[7][r]);
            }
        }
    }

    // ---- epilogue: 3-round LDS tree-combine (reuses qf region) ----
    __syncthreads();                       // qf reads done everywhere
    float* epi = (float*)(smem + kQOff);   // 4 slots x 2048 floats

    if (wave >= 4) {
        #pragma unroll
        for (int dt = 0; dt < 8; ++dt)
            *(f32x4*)&epi[(wave - 4) * 2048 + dt * 256 + lane * 4] = oacc[dt];
    }
    __syncthreads();
    if (wave < 4) {
        #pragma unroll
        for (int dt = 0; dt < 8; ++dt) {
            const f32x4 o = *(const f32x4*)&epi[wave * 2048 + dt * 256 + lane * 4];
            #pragma unroll
            for (int r = 0; r < 4; ++r) oacc[dt][r] += o[r];
        }
    }
    __syncthreads();
    if (wave == 2 || wave == 3) {
        #pragma unroll
        for (int dt = 0; dt < 8; ++dt)
            *(f32x4*)&epi[(wave - 2) * 2048 + dt * 256 + lane * 4] = oacc[dt];
    }
    __syncthreads();
    if (wave < 2) {
        #pragma unroll
        for (int dt = 0; dt < 8; ++dt) {
            const f32x4 o = *(const f32x4*)&epi[wave * 2048 + dt * 256 + lane * 4];
            #pragma unroll
            for (int r = 0; r < 4; ++r) oacc[dt][r] += o[r];
        }
    }
    __syncthreads();
    if (wave == 1) {
        #pragma unroll
        for (int dt = 0; dt < 8; ++dt)
            *(f32x4*)&epi[dt * 256 + lane * 4] = oacc[dt];
    }
    __syncthreads();
    if (wave == 0) {
        float* ob = out + ((size_t)l * kHQ + h * kG + n) * kD;
        #pragma unroll
        for (int dt = 0; dt < 8; ++dt) {
            const f32x4 o = *(const f32x4*)&epi[dt * 256 + lane * 4];
            f32x4 val;
            #pragma unroll
            for (int r = 0; r < 4; ++r) val[r] = oacc[dt][r] + o[r];
            __builtin_nontemporal_store(val, (f32x4*)(ob + dt * 16 + quad * 4));
        }
    }
}

} // namespace

extern "C" void kernel_launch(void* const* d_in, const int* in_sizes, int n_in,
                              void* d_out, int out_size, void* d_ws, size_t ws_size,
                              hipStream_t stream)
{
    const float* q    = (const float*)d_in[0];
    const float* k    = (const float*)d_in[1];
    const float* v    = (const float*)d_in[2];
    const float* w    = (const float*)d_in[3];
    const int*   bidx = (const int*)d_in[4];
    float* out = (float*)d_out;

    uint4* kp = (uint4*)d_ws;                                   // 2 MB
    uint4* vp = (uint4*)((char*)d_ws + (size_t)kKPackN * 16);   // 2 MB

    hsa_fused<<<dim3(kGrid), dim3(512), 0, stream>>>(q, k, v, w, bidx, kp, vp, out);
}

// Round 6
// 99.267 us; speedup vs baseline: 1.4580x; 1.4580x over previous
//
#include <hip/hip_runtime.h>
#include <hip/hip_bf16.h>

// HSA prefill R20 (resubmit; R5 bench was a GPU-broker timeout, no data).
// R20: revert fusion (R19: fused VGPR collapsed to 64 -> serialized
// streams, 82us; split main ran ~120 VGPR). Keep split pack.
// Restructure main around the now-confirmed latency-bound regime
// (R19 counters: MfmaUtil 1.9%, VALUBusy 5.3%, HBM 3.7% -> ~95% stall):
//   (1) PV transposed: each wave owns ONE 16-wide d-tile (dt = wave) across
//       ALL 16 s-blocks (P slices are in LDS, readable by all waves).
//       -> tree-combine epilogue GONE: 5 __syncthreads + 3 LDS round-trips
//          -> ONE barrier total; each wave stores its own out columns.
//   (2) PV = 16 independent 2-MFMA chains, 4-deep V-load pipeline
//       (vs 4 dependent v-groups) -> latency overlap per wave.
//   (3) oacc 32->4 VGPR, LDS 68->42 KB (shared qf slice - all waves write
//       identical bytes, benign race; no epilogue scratch; P stride 72->74
//       shorts: PV bf-read banks (5n+4q) mod 32 -> <=2-way, free).
//       Target: VGPR<=84 + LDS 42KB -> 3 blocks/CU = 24 waves (1.5x TLP).
// Scores phase, pack kernel, XCD-h swizzle, nt loads/stores: unchanged.

namespace {

constexpr int kLq = 256, kHQ = 32, kH = 2, kG = 16, kD = 128, kS = 16;
constexpr int kNB = 64;                    // Lkv/BS: distinct blocks per head
constexpr float kScaleLog2e = 0.08838834764831845f * 1.4426950408889634f;

constexpr int kKPackN = kH * kNB * 16 * 64;  // uint4 elems per array (2 MB)
constexpr int kPStr   = 74;                  // P row stride (shorts)
constexpr int kPBlk   = 16 * kPStr;          // shorts per s-block slice (1184)
constexpr int kPWave  = 2 * kPBlk;           // shorts per wave (2368 = 4736 B)
constexpr int kSStr   = 136;                 // pack LDS row stride (shorts)

// main LDS layout (bytes), total 43008:
//   [0, 1024)      coef[s][n] f32  (16 x 16)
//   [1024, 5120)   qf shared slice: st*1024 + lane*16 (all waves, same bytes)
//   [5120, 43008)  P slices: wave*4736 + blk*2368 + (n*74 + u)*2
constexpr int kCoefOff = 0;
constexpr int kQOff    = 1024;
constexpr int kPOff    = 5120;

typedef short s16x8 __attribute__((ext_vector_type(8)));
typedef float f32x4 __attribute__((ext_vector_type(4)));

union U32BF2 { unsigned int u; __hip_bfloat162 h; };
union FragU  { uint4 u; s16x8 v; };

static __device__ inline unsigned int pk_bf16(float a, float b) {
    U32BF2 z; z.h = __float22bfloat162_rn(make_float2(a, b));
    return z.u;
}

// ---------------- pack kernel (R18 split version, unchanged) --------------
// K_packed idx = ((h*64+blk)*16 + t*4+st)*64 + lane (lane = quad*16+n)
//   holds K[u = blk*64 + t*16 + n][h][d = st*32 + quad*8 + j]
// V_packed idx = ((h*64+blk)*16 + dt*2+st)*64 + lane
//   holds V[u = blk*64 + st*32 + quad*8 + j][h][d = dt*16 + n]
__global__ __launch_bounds__(256)
void pack_kv(const float* __restrict__ k, const float* __restrict__ v,
             uint4* __restrict__ kp, uint4* __restrict__ vp)
{
    __shared__ unsigned short S_s[32 * kSStr];   // 8.7 KB bf16 [u_loc][d]

    const int bid  = blockIdx.x;                 // 0..511
    const int isV  = bid & 1;
    const int half = (bid >> 1) & 1;
    const int blk  = (bid >> 2) & 63;
    const int h    = bid >> 8;
    const int t    = threadIdx.x;
    const int lane = t & 63, n = lane & 15, quad = lane >> 4;
    const int wv   = t >> 6;                     // 0..3

    {   // coalesced load 32 rows x 128 fp32 -> bf16 LDS (nt: read-once)
        const float* src = (isV ? v : k) +
            ((size_t)(blk * 64 + half * 32) * kH + h) * kD;
        const int r0 = t >> 5, c4 = (t & 31) << 2;
        #pragma unroll
        for (int p = 0; p < 4; ++p) {
            const int r = p * 8 + r0;
            const f32x4 f = __builtin_nontemporal_load(
                (const f32x4*)(src + (size_t)r * (kH * kD) + c4));
            *(unsigned int*)&S_s[r * kSStr + c4]     = pk_bf16(f[0], f[1]);
            *(unsigned int*)&S_s[r * kSStr + c4 + 2] = pk_bf16(f[2], f[3]);
        }
    }
    __syncthreads();

    const size_t obase = (size_t)(h * 64 + blk) * 16 * 64;
    if (!isV) {
        #pragma unroll
        for (int rep = 0; rep < 2; ++rep) {
            const int cl    = wv * 2 + rep;      // 0..7
            const int t_loc = cl >> 2, st = cl & 3;
            const int c     = (2 * half + t_loc) * 4 + st;
            const int u_loc = t_loc * 16 + n;
            kp[obase + (size_t)c * 64 + lane] =
                *(const uint4*)&S_s[u_loc * kSStr + st * 32 + quad * 8];
        }
    } else {
        #pragma unroll
        for (int rep = 0; rep < 2; ++rep) {
            const int dt = wv * 2 + rep;         // 0..7
            const int c  = dt * 2 + half;
            const int d  = dt * 16 + n;
            unsigned short s[8];
            #pragma unroll
            for (int j = 0; j < 8; ++j) s[j] = S_s[(quad * 8 + j) * kSStr + d];
            uint4 val;
            val.x = s[0] | ((unsigned)s[1] << 16);
            val.y = s[2] | ((unsigned)s[3] << 16);
            val.z = s[4] | ((unsigned)s[5] << 16);
            val.w = s[6] | ((unsigned)s[7] << 16);
            vp[obase + (size_t)c * 64 + lane] = val;
        }
    }
}

// ---------------- main kernel --------------------------------------------
__global__ __launch_bounds__(512, 4)
void hsa_main(const float* __restrict__ q, const float* __restrict__ w,
              const int* __restrict__ bidx, const uint4* __restrict__ kp,
              const uint4* __restrict__ vp, float* __restrict__ out)
{
    __shared__ __align__(16) unsigned char smem[43008];   // 42 KB (see layout)

    const int bid  = blockIdx.x;                 // 0..511
    const int xcd  = bid & 7;                    // XCD-h swizzle (R18)
    const int h    = xcd >> 2;
    const int l    = (bid >> 3) * 4 + (xcd & 3);
    const int tid  = threadIdx.x;
    const int wave = tid >> 6;                   // 0..7
    const int lane = tid & 63;
    const int n    = lane & 15;
    const int quad = lane >> 4;

    // ---- per-lane block index -> per-lane base (lane s carries s-block s) --
    const int bv     = bidx[(size_t)(l * kH + h) * kS + n];   // quads identical
    const int baseSv = (h * kNB + max(bv, 0)) * 1024;

    // ---- Q B-frags -> SHARED qf slice (benign identical-write race:
    //      every wave writes the same bytes; own writes precede own reads) --
    unsigned char* qlds = smem + kQOff + lane * 16;
    {
        const float* qb = q + ((size_t)l * kHQ + h * kG + n) * kD + quad * 8;
        #pragma unroll
        for (int st = 0; st < 4; ++st) {
            const f32x4 f0 = __builtin_nontemporal_load((const f32x4*)(qb + st * 32));
            const f32x4 f1 = __builtin_nontemporal_load((const f32x4*)(qb + st * 32 + 4));
            uint4 z;
            z.x = pk_bf16(f0[0], f0[1]); z.y = pk_bf16(f0[2], f0[3]);
            z.z = pk_bf16(f1[0], f1[1]); z.w = pk_bf16(f1[2], f1[3]);
            *(uint4*)(qlds + st * 1024) = z;
        }
    }

    // ---- this wave's 2 s-blocks A,B: s = wave*2 + {0,1} ----
    const int sA = wave * 2, sB = wave * 2 + 1;
    const int biA = __builtin_amdgcn_readlane(bv, sA);
    const int biB = __builtin_amdgcn_readlane(bv, sB);
    const int baseA = __builtin_amdgcn_readlane(baseSv, sA);
    const int baseB = __builtin_amdgcn_readlane(baseSv, sB);
    const float wvalA =
        (biA < 0) ? 0.f : w[((size_t)l * kHQ + h * kG + n) * kS + sA];
    const float wvalB =
        (biB < 0) ? 0.f : w[((size_t)l * kHQ + h * kG + n) * kS + sB];

    unsigned short* PA = (unsigned short*)(smem + kPOff) + wave * kPWave;
    unsigned short* PB = PA + kPBlk;

    // prologue: kA <- A-K-g0, kB <- B-K-g0 (8 loads in flight)
    FragU kA[4], kB[4];
    #pragma unroll
    for (int st = 0; st < 4; ++st) kA[st].u = kp[baseA + st * 64 + lane];
    #pragma unroll
    for (int st = 0; st < 4; ++st) kB[st].u = kp[baseB + st * 64 + lane];
    __builtin_amdgcn_sched_barrier(0);

    // ---- interleaved scores: A-t, B-t alternate (refill distance ~1 group) --
    float partA = 0.f, partB = 0.f;
    #pragma unroll
    for (int t = 0; t < 4; ++t) {
        {   // A group t
            f32x4 sc = {0.f, 0.f, 0.f, 0.f};
            #pragma unroll
            for (int st = 0; st < 4; ++st) {
                const s16x8 aq = *(const s16x8*)(qlds + st * 1024);
                sc = __builtin_amdgcn_mfma_f32_16x16x32_bf16(kA[st].v, aq, sc, 0, 0, 0);
            }
            if (t < 3) {
                #pragma unroll
                for (int st = 0; st < 4; ++st)
                    kA[st].u = kp[baseA + ((t + 1) * 4 + st) * 64 + lane];
            }
            __builtin_amdgcn_sched_barrier(0);
            #pragma unroll
            for (int r = 0; r < 4; ++r) {
                sc[r] = exp2f(sc[r] * kScaleLog2e);
                partA += sc[r];
            }
            const unsigned long long pq =
                ((unsigned long long)pk_bf16(sc[2], sc[3]) << 32) | pk_bf16(sc[0], sc[1]);
            *(unsigned long long*)&PA[n * kPStr + t * 16 + quad * 4] = pq;
        }
        {   // B group t
            f32x4 sc = {0.f, 0.f, 0.f, 0.f};
            #pragma unroll
            for (int st = 0; st < 4; ++st) {
                const s16x8 aq = *(const s16x8*)(qlds + st * 1024);
                sc = __builtin_amdgcn_mfma_f32_16x16x32_bf16(kB[st].v, aq, sc, 0, 0, 0);
            }
            if (t < 3) {
                #pragma unroll
                for (int st = 0; st < 4; ++st)
                    kB[st].u = kp[baseB + ((t + 1) * 4 + st) * 64 + lane];
            }
            __builtin_amdgcn_sched_barrier(0);
            #pragma unroll
            for (int r = 0; r < 4; ++r) {
                sc[r] = exp2f(sc[r] * kScaleLog2e);
                partB += sc[r];
            }
            const unsigned long long pq =
                ((unsigned long long)pk_bf16(sc[2], sc[3]) << 32) | pk_bf16(sc[0], sc[1]);
            *(unsigned long long*)&PB[n * kPStr + t * 16 + quad * 4] = pq;
        }
    }

    // ---- PV prefetch: own d-tile (dt = wave), s = 0..3, 8 loads in flight.
    //      They drain at the barrier's vmcnt(0) -> overlapped with the
    //      slowest wave's scores tail.
    const int cOff0 = wave * 2 * 64 + lane;      // chunk (2*wave,   lane)
    const int cOff1 = cOff0 + 64;                // chunk (2*wave+1, lane)
    FragU v0[4], v1[4];
    #pragma unroll
    for (int s = 0; s < 4; ++s) {
        const int bs = __builtin_amdgcn_readlane(baseSv, s);
        v0[s].u = vp[bs + cOff0];
        v1[s].u = vp[bs + cOff1];
    }
    __builtin_amdgcn_sched_barrier(0);

    // ---- intra-wave denominators + coef table ----
    partA += __shfl_xor(partA, 16);
    partA += __shfl_xor(partA, 32);
    partB += __shfl_xor(partB, 16);
    partB += __shfl_xor(partB, 32);
    float* coefT = (float*)(smem + kCoefOff);
    if (quad == 0) {
        coefT[sA * 16 + n] = wvalA / partA;
        coefT[sB * 16 + n] = wvalB / partB;
    }

    __syncthreads();   // the ONLY barrier: P slices + coef visible to all

    // ---- PV: 16 independent s-chains, wave owns d-tile dt = wave ----
    const f32x4 zero = {0.f, 0.f, 0.f, 0.f};
    f32x4 oacc = zero;
    #pragma unroll
    for (int s = 0; s < 16; ++s) {
        const int slot = s & 3;
        const unsigned short* Ps =
            (const unsigned short*)(smem + kPOff) + (s >> 1) * kPWave + (s & 1) * kPBlk;
        const s16x8 bf0 = *(const s16x8*)&Ps[n * kPStr + quad * 8];
        const s16x8 bf1 = *(const s16x8*)&Ps[n * kPStr + 32 + quad * 8];
        const float c   = coefT[s * 16 + n];
        f32x4 p = __builtin_amdgcn_mfma_f32_16x16x32_bf16(v0[slot].v, bf0, zero, 0, 0, 0);
        p       = __builtin_amdgcn_mfma_f32_16x16x32_bf16(v1[slot].v, bf1, p,    0, 0, 0);
        if (s < 12) {   // refill distance 4 chains (~>= L3 latency)
            const int bs = __builtin_amdgcn_readlane(baseSv, s + 4);
            v0[slot].u = vp[bs + cOff0];
            v1[slot].u = vp[bs + cOff1];
        }
        __builtin_amdgcn_sched_barrier(0);
        #pragma unroll
        for (int r = 0; r < 4; ++r) oacc[r] = fmaf(c, p[r], oacc[r]);
    }

    // ---- direct store: wave owns out[.., n, wave*16 + quad*4 .. +3] ----
    float* ob = out + ((size_t)l * kHQ + h * kG + n) * kD + wave * 16 + quad * 4;
    __builtin_nontemporal_store(oacc, (f32x4*)ob);
}

} // namespace

extern "C" void kernel_launch(void* const* d_in, const int* in_sizes, int n_in,
                              void* d_out, int out_size, void* d_ws, size_t ws_size,
                              hipStream_t stream)
{
    const float* q    = (const float*)d_in[0];
    const float* k    = (const float*)d_in[1];
    const float* v    = (const float*)d_in[2];
    const float* w    = (const float*)d_in[3];
    const int*   bidx = (const int*)d_in[4];
    float* out = (float*)d_out;

    uint4* kp = (uint4*)d_ws;                                   // 2 MB
    uint4* vp = (uint4*)((char*)d_ws + (size_t)kKPackN * 16);   // 2 MB

    pack_kv<<<dim3(512), dim3(256), 0, stream>>>(k, v, kp, vp);
    hsa_main<<<dim3(kLq * kH), dim3(512), 0, stream>>>(q, w, bidx, kp, vp, out);
}

// Round 7
// 95.301 us; speedup vs baseline: 1.5187x; 1.0416x over previous
//
#include <hip/hip_runtime.h>
#include <hip/hip_bf16.h>

// HSA prefill R21 = R17 structure + doubled stream depths (within 128 VGPR).
// R20 post-mortem (99.3us, +10.5 vs R17): mid-kernel barrier convoyed
// scores/PV (killed R17's barrier-free overlap) + per-iteration ds_read with
// sched_barrier serialized PV. Reverted. R19's datapoint (VGPR64 serialized
// = 82us vs VGPR~120 deep = ~40us) says per-wave load-pipeline depth is THE
// lever in this latency-bound regime (MfmaUtil 1.9%, VALUBusy 5.3%, HBM 4%).
// R21 deepens both phases via phase-disjoint register lifetimes:
//   scores: 4 K-banks kA0/kB0/kA1/kB1 (64 VGPR), refill distance 2 t-steps
//           (~3 interleaved groups ~900cy cover vs ~300 in R17).
//   PV:     4 V-banks vr0..vr3 (64 VGPR), refill distance 3 v-groups
//           (~500cy vs R17's 2). K banks die at scores end -> allocator
//           reuses those regs for vr2/vr3/oacc (oacc init moved after
//           scores). Peak ~116-124 VGPR both phases; launch_bounds(512,4)
//           cap 128 holds 2 blocks/CU. Everything else R17 verbatim
//           (barrier-free main loop, qf in LDS, dual P slices, 5-barrier
//           tree epilogue, kPStr=72).

namespace {

constexpr int kLq = 256, kHQ = 32, kH = 2, kG = 16, kD = 128, kS = 16;
constexpr int kNB = 64;                    // Lkv/BS: distinct blocks per head
constexpr float kScaleLog2e = 0.08838834764831845f * 1.4426950408889634f;

constexpr int kKPackN = kH * kNB * 16 * 64;  // uint4 elems per array (2 MB)
constexpr int kPStr   = 72;                  // P row stride (shorts)
constexpr int kSStr   = 136;                 // pack LDS row stride (shorts)

// main-kernel LDS layout (bytes):
//   [0, 32768)        qf slices:  wave*4096 + st*1024 + lane*16   (epilogue reuse)
//   [32768, 69632)    P slices:   wave*4608 + blk*2304 + (n*72+u)*2
constexpr int kQOff = 0;
constexpr int kPOff = 32768;

typedef short s16x8 __attribute__((ext_vector_type(8)));
typedef float f32x4 __attribute__((ext_vector_type(4)));

union U32BF2 { unsigned int u; __hip_bfloat162 h; };
union FragU  { uint4 u; s16x8 v; };

static __device__ inline unsigned int pk_bf16(float a, float b) {
    U32BF2 z; z.h = __float22bfloat162_rn(make_float2(a, b));
    return z.u;
}

// ---------------- pack kernel (R17 verbatim, 512 wgs, ~5 us) ---------------
// K_packed idx = ((h*64+blk)*16 + t*4+st)*64 + lane (lane = quad*16+n)
//   holds K[u = blk*64 + t*16 + n][h][d = st*32 + quad*8 + j]
// V_packed idx = ((h*64+blk)*16 + dt*2+st)*64 + lane
//   holds V[u = blk*64 + st*32 + quad*8 + j][h][d = dt*16 + n]
__global__ __launch_bounds__(256)
void pack_kv(const float* __restrict__ k, const float* __restrict__ v,
             uint4* __restrict__ kp, uint4* __restrict__ vp)
{
    __shared__ unsigned short S_s[32 * kSStr];   // 8.7 KB bf16 [u_loc][d]

    const int bid  = blockIdx.x;                 // 0..511
    const int isV  = bid & 1;
    const int half = (bid >> 1) & 1;
    const int blk  = (bid >> 2) & 63;
    const int h    = bid >> 8;
    const int t    = threadIdx.x;
    const int lane = t & 63, n = lane & 15, quad = lane >> 4;
    const int wv   = t >> 6;                     // 0..3

    {   // coalesced load 32 rows x 128 fp32 -> bf16 LDS
        const float* src = (isV ? v : k) +
            ((size_t)(blk * 64 + half * 32) * kH + h) * kD;
        const int r0 = t >> 5, c4 = (t & 31) << 2;
        #pragma unroll
        for (int p = 0; p < 4; ++p) {
            const int r = p * 8 + r0;
            const float4 f = *(const float4*)(src + (size_t)r * (kH * kD) + c4);
            *(unsigned int*)&S_s[r * kSStr + c4]     = pk_bf16(f.x, f.y);
            *(unsigned int*)&S_s[r * kSStr + c4 + 2] = pk_bf16(f.z, f.w);
        }
    }
    __syncthreads();

    const size_t obase = (size_t)(h * 64 + blk) * 16 * 64;
    if (!isV) {
        #pragma unroll
        for (int rep = 0; rep < 2; ++rep) {
            const int cl    = wv * 2 + rep;      // 0..7
            const int t_loc = cl >> 2, st = cl & 3;
            const int c     = (2 * half + t_loc) * 4 + st;
            const int u_loc = t_loc * 16 + n;
            kp[obase + (size_t)c * 64 + lane] =
                *(const uint4*)&S_s[u_loc * kSStr + st * 32 + quad * 8];
        }
    } else {
        #pragma unroll
        for (int rep = 0; rep < 2; ++rep) {
            const int dt = wv * 2 + rep;         // 0..7
            const int c  = dt * 2 + half;
            const int d  = dt * 16 + n;
            unsigned short s[8];
            #pragma unroll
            for (int j = 0; j < 8; ++j) s[j] = S_s[(quad * 8 + j) * kSStr + d];
            uint4 val;
            val.x = s[0] | ((unsigned)s[1] << 16);
            val.y = s[2] | ((unsigned)s[3] << 16);
            val.z = s[4] | ((unsigned)s[5] << 16);
            val.w = s[6] | ((unsigned)s[7] << 16);
            vp[obase + (size_t)c * 64 + lane] = val;
        }
    }
}

// ---------------- main kernel --------------------------------------------
__global__ __launch_bounds__(512, 4)
void hsa_main(const float* __restrict__ q, const float* __restrict__ w,
              const int* __restrict__ bidx, const uint4* __restrict__ kp,
              const uint4* __restrict__ vp, float* __restrict__ out)
{
    __shared__ __align__(16) unsigned char smem[69632];   // 68 KB (see layout)

    const int bid  = blockIdx.x;                 // 0..511
    const int l    = bid >> 1;
    const int h    = bid & 1;
    const int tid  = threadIdx.x;
    const int wave = tid >> 6;                   // 0..7
    const int lane = tid & 63;
    const int n    = lane & 15;
    const int quad = lane >> 4;

    // ---- Q B-frags -> per-wave LDS slice (frees 16 VGPR) ----
    unsigned char* qlds = smem + kQOff + wave * 4096 + lane * 16;
    {
        const float* qb = q + ((size_t)l * kHQ + h * kG + n) * kD + quad * 8;
        #pragma unroll
        for (int st = 0; st < 4; ++st) {
            const float4 f0 = *(const float4*)(qb + st * 32);
            const float4 f1 = *(const float4*)(qb + st * 32 + 4);
            uint4 z;
            z.x = pk_bf16(f0.x, f0.y); z.y = pk_bf16(f0.z, f0.w);
            z.z = pk_bf16(f1.x, f1.y); z.w = pk_bf16(f1.z, f1.w);
            *(uint4*)(qlds + st * 1024) = z;
        }
    }

    // this wave's 2 s-blocks A,B: s = wave*2 + {0,1}
    int   baseA, baseB;
    float wvalA, wvalB;
    {
        const int sA = wave * 2, sB = wave * 2 + 1;
        const int biA = bidx[(size_t)(l * kH + h) * kS + sA];
        const int biB = bidx[(size_t)(l * kH + h) * kS + sB];
        wvalA = (biA < 0) ? 0.f : w[((size_t)l * kHQ + h * kG + n) * kS + sA];
        wvalB = (biB < 0) ? 0.f : w[((size_t)l * kHQ + h * kG + n) * kS + sB];
        baseA = (h * kNB + max(biA, 0)) * 1024;
        baseB = (h * kNB + max(biB, 0)) * 1024;
    }

    unsigned short* PA = (unsigned short*)(smem + kPOff + wave * 4608);
    unsigned short* PB = PA + kG * kPStr;

    // prologue: kA0<-A-K-g0, kB0<-B-K-g0, kA1<-A-K-g1, kB1<-B-K-g1,
    //           vr0<-A-V-g0, vr1<-A-V-g1   (24 loads in flight; vr banks
    //           drain under the whole scores phase)
    FragU kA0[4], kB0[4], kA1[4], kB1[4], vr0[4], vr1[4];
    #pragma unroll
    for (int st = 0; st < 4; ++st) kA0[st].u = kp[baseA + st * 64 + lane];
    #pragma unroll
    for (int st = 0; st < 4; ++st) kB0[st].u = kp[baseB + st * 64 + lane];
    #pragma unroll
    for (int st = 0; st < 4; ++st) kA1[st].u = kp[baseA + (4 + st) * 64 + lane];
    #pragma unroll
    for (int st = 0; st < 4; ++st) kB1[st].u = kp[baseB + (4 + st) * 64 + lane];
    #pragma unroll
    for (int i = 0; i < 4; ++i)    vr0[i].u = vp[baseA + i * 64 + lane];
    #pragma unroll
    for (int i = 0; i < 4; ++i)    vr1[i].u = vp[baseA + (4 + i) * 64 + lane];
    __builtin_amdgcn_sched_barrier(0);

    // ---- interleaved scores: A-t, B-t alternate; 4 K-banks, refill
    //      distance 2 t-steps (~3 interleaved groups of cover) ----
    float partA = 0.f, partB = 0.f;
    #pragma unroll
    for (int t = 0; t < 4; ++t) {
        FragU* bkA = (t & 1) ? kA1 : kA0;
        FragU* bkB = (t & 1) ? kB1 : kB0;
        {   // A group t
            f32x4 sc = {0.f, 0.f, 0.f, 0.f};
            #pragma unroll
            for (int st = 0; st < 4; ++st) {
                const s16x8 aq = *(const s16x8*)(qlds + st * 1024);
                sc = __builtin_amdgcn_mfma_f32_16x16x32_bf16(bkA[st].v, aq, sc, 0, 0, 0);
            }
            if (t < 2) {
                #pragma unroll
                for (int st = 0; st < 4; ++st)
                    bkA[st].u = kp[baseA + ((t + 2) * 4 + st) * 64 + lane];
            }
            __builtin_amdgcn_sched_barrier(0);
            #pragma unroll
            for (int r = 0; r < 4; ++r) {
                sc[r] = exp2f(sc[r] * kScaleLog2e);
                partA += sc[r];
            }
            const unsigned long long pq =
                ((unsigned long long)pk_bf16(sc[2], sc[3]) << 32) | pk_bf16(sc[0], sc[1]);
            *(unsigned long long*)&PA[n * kPStr + t * 16 + quad * 4] = pq;
        }
        {   // B group t
            f32x4 sc = {0.f, 0.f, 0.f, 0.f};
            #pragma unroll
            for (int st = 0; st < 4; ++st) {
                const s16x8 aq = *(const s16x8*)(qlds + st * 1024);
                sc = __builtin_amdgcn_mfma_f32_16x16x32_bf16(bkB[st].v, aq, sc, 0, 0, 0);
            }
            if (t < 2) {
                #pragma unroll
                for (int st = 0; st < 4; ++st)
                    bkB[st].u = kp[baseB + ((t + 2) * 4 + st) * 64 + lane];
            }
            __builtin_amdgcn_sched_barrier(0);
            #pragma unroll
            for (int r = 0; r < 4; ++r) {
                sc[r] = exp2f(sc[r] * kScaleLog2e);
                partB += sc[r];
            }
            const unsigned long long pq =
                ((unsigned long long)pk_bf16(sc[2], sc[3]) << 32) | pk_bf16(sc[0], sc[1]);
            *(unsigned long long*)&PB[n * kPStr + t * 16 + quad * 4] = pq;
        }
    }

    // K banks dead from here: allocator reuses those 64 VGPR for vr2/vr3
    // (issued now, consumed at A-vg2/vg3) and oacc.
    FragU vr2[4], vr3[4];
    #pragma unroll
    for (int i = 0; i < 4; ++i) vr2[i].u = vp[baseA + (8 + i) * 64 + lane];
    #pragma unroll
    for (int i = 0; i < 4; ++i) vr3[i].u = vp[baseA + (12 + i) * 64 + lane];
    __builtin_amdgcn_sched_barrier(0);

    // ---- intra-wave denominators ----
    partA += __shfl_xor(partA, 16);
    partA += __shfl_xor(partA, 32);
    partB += __shfl_xor(partB, 16);
    partB += __shfl_xor(partB, 32);
    const float coefA = wvalA / partA;
    const float coefB = wvalB / partB;

    f32x4 oacc[8];
    #pragma unroll
    for (int dt = 0; dt < 8; ++dt) oacc[dt] = (f32x4){0.f, 0.f, 0.f, 0.f};

    const f32x4 zero = {0.f, 0.f, 0.f, 0.f};

    // ---- PV(A): vrj holds A-V-gj -> d-tiles 2j,2j+1; refill vrj <- B-V-gj
    //      (refill distance 3 v-groups ~500 cy) ----
    {
        const s16x8 bf0 = *(const s16x8*)&PA[n * kPStr + quad * 8];
        const s16x8 bf1 = *(const s16x8*)&PA[n * kPStr + 32 + quad * 8];

        // vg0: vr0 -> d-tiles 0,1 ; refill vr0 <- B-g0
        {
            f32x4 p0 = __builtin_amdgcn_mfma_f32_16x16x32_bf16(vr0[0].v, bf0, zero, 0, 0, 0);
            p0       = __builtin_amdgcn_mfma_f32_16x16x32_bf16(vr0[1].v, bf1, p0,   0, 0, 0);
            f32x4 p1 = __builtin_amdgcn_mfma_f32_16x16x32_bf16(vr0[2].v, bf0, zero, 0, 0, 0);
            p1       = __builtin_amdgcn_mfma_f32_16x16x32_bf16(vr0[3].v, bf1, p1,   0, 0, 0);
            #pragma unroll
            for (int i = 0; i < 4; ++i) vr0[i].u = vp[baseB + i * 64 + lane];
            __builtin_amdgcn_sched_barrier(0);
            #pragma unroll
            for (int r = 0; r < 4; ++r) {
                oacc[0][r] = fmaf(coefA, p0[r], oacc[0][r]);
                oacc[1][r] = fmaf(coefA, p1[r], oacc[1][r]);
            }
        }
        // vg1: vr1 -> d-tiles 2,3 ; refill vr1 <- B-g1
        {
            f32x4 p0 = __builtin_amdgcn_mfma_f32_16x16x32_bf16(vr1[0].v, bf0, zero, 0, 0, 0);
            p0       = __builtin_amdgcn_mfma_f32_16x16x32_bf16(vr1[1].v, bf1, p0,   0, 0, 0);
            f32x4 p1 = __builtin_amdgcn_mfma_f32_16x16x32_bf16(vr1[2].v, bf0, zero, 0, 0, 0);
            p1       = __builtin_amdgcn_mfma_f32_16x16x32_bf16(vr1[3].v, bf1, p1,   0, 0, 0);
            #pragma unroll
            for (int i = 0; i < 4; ++i) vr1[i].u = vp[baseB + (4 + i) * 64 + lane];
            __builtin_amdgcn_sched_barrier(0);
            #pragma unroll
            for (int r = 0; r < 4; ++r) {
                oacc[2][r] = fmaf(coefA, p0[r], oacc[2][r]);
                oacc[3][r] = fmaf(coefA, p1[r], oacc[3][r]);
            }
        }
        // vg2: vr2 -> d-tiles 4,5 ; refill vr2 <- B-g2
        {
            f32x4 p0 = __builtin_amdgcn_mfma_f32_16x16x32_bf16(vr2[0].v, bf0, zero, 0, 0, 0);
            p0       = __builtin_amdgcn_mfma_f32_16x16x32_bf16(vr2[1].v, bf1, p0,   0, 0, 0);
            f32x4 p1 = __builtin_amdgcn_mfma_f32_16x16x32_bf16(vr2[2].v, bf0, zero, 0, 0, 0);
            p1       = __builtin_amdgcn_mfma_f32_16x16x32_bf16(vr2[3].v, bf1, p1,   0, 0, 0);
            #pragma unroll
            for (int i = 0; i < 4; ++i) vr2[i].u = vp[baseB + (8 + i) * 64 + lane];
            __builtin_amdgcn_sched_barrier(0);
            #pragma unroll
            for (int r = 0; r < 4; ++r) {
                oacc[4][r] = fmaf(coefA, p0[r], oacc[4][r]);
                oacc[5][r] = fmaf(coefA, p1[r], oacc[5][r]);
            }
        }
        // vg3: vr3 -> d-tiles 6,7 ; refill vr3 <- B-g3
        {
            f32x4 p0 = __builtin_amdgcn_mfma_f32_16x16x32_bf16(vr3[0].v, bf0, zero, 0, 0, 0);
            p0       = __builtin_amdgcn_mfma_f32_16x16x32_bf16(vr3[1].v, bf1, p0,   0, 0, 0);
            f32x4 p1 = __builtin_amdgcn_mfma_f32_16x16x32_bf16(vr3[2].v, bf0, zero, 0, 0, 0);
            p1       = __builtin_amdgcn_mfma_f32_16x16x32_bf16(vr3[3].v, bf1, p1,   0, 0, 0);
            #pragma unroll
            for (int i = 0; i < 4; ++i) vr3[i].u = vp[baseB + (12 + i) * 64 + lane];
            __builtin_amdgcn_sched_barrier(0);
            #pragma unroll
            for (int r = 0; r < 4; ++r) {
                oacc[6][r] = fmaf(coefA, p0[r], oacc[6][r]);
                oacc[7][r] = fmaf(coefA, p1[r], oacc[7][r]);
            }
        }
    }

    // ---- PV(B): vrj holds B-V-gj -> d-tiles 2j,2j+1 (no refills) ----
    {
        const s16x8 bf0 = *(const s16x8*)&PB[n * kPStr + quad * 8];
        const s16x8 bf1 = *(const s16x8*)&PB[n * kPStr + 32 + quad * 8];

        {
            f32x4 p0 = __builtin_amdgcn_mfma_f32_16x16x32_bf16(vr0[0].v, bf0, zero, 0, 0, 0);
            p0       = __builtin_amdgcn_mfma_f32_16x16x32_bf16(vr0[1].v, bf1, p0,   0, 0, 0);
            f32x4 p1 = __builtin_amdgcn_mfma_f32_16x16x32_bf16(vr0[2].v, bf0, zero, 0, 0, 0);
            p1       = __builtin_amdgcn_mfma_f32_16x16x32_bf16(vr0[3].v, bf1, p1,   0, 0, 0);
            #pragma unroll
            for (int r = 0; r < 4; ++r) {
                oacc[0][r] = fmaf(coefB, p0[r], oacc[0][r]);
                oacc[1][r] = fmaf(coefB, p1[r], oacc[1][r]);
            }
        }
        {
            f32x4 p0 = __builtin_amdgcn_mfma_f32_16x16x32_bf16(vr1[0].v, bf0, zero, 0, 0, 0);
            p0       = __builtin_amdgcn_mfma_f32_16x16x32_bf16(vr1[1].v, bf1, p0,   0, 0, 0);
            f32x4 p1 = __builtin_amdgcn_mfma_f32_16x16x32_bf16(vr1[2].v, bf0, zero, 0, 0, 0);
            p1       = __builtin_amdgcn_mfma_f32_16x16x32_bf16(vr1[3].v, bf1, p1,   0, 0, 0);
            #pragma unroll
            for (int r = 0; r < 4; ++r) {
                oacc[2][r] = fmaf(coefB, p0[r], oacc[2][r]);
                oacc[3][r] = fmaf(coefB, p1[r], oacc[3][r]);
            }
        }
        {
            f32x4 p0 = __builtin_amdgcn_mfma_f32_16x16x32_bf16(vr2[0].v, bf0, zero, 0, 0, 0);
            p0       = __builtin_amdgcn_mfma_f32_16x16x32_bf16(vr2[1].v, bf1, p0,   0, 0, 0);
            f32x4 p1 = __builtin_amdgcn_mfma_f32_16x16x32_bf16(vr2[2].v, bf0, zero, 0, 0, 0);
            p1       = __builtin_amdgcn_mfma_f32_16x16x32_bf16(vr2[3].v, bf1, p1,   0, 0, 0);
            #pragma unroll
            for (int r = 0; r < 4; ++r) {
                oacc[4][r] = fmaf(coefB, p0[r], oacc[4][r]);
                oacc[5][r] = fmaf(coefB, p1[r], oacc[5][r]);
            }
        }
        {
            f32x4 p0 = __builtin_amdgcn_mfma_f32_16x16x32_bf16(vr3[0].v, bf0, zero, 0, 0, 0);
            p0       = __builtin_amdgcn_mfma_f32_16x16x32_bf16(vr3[1].v, bf1, p0,   0, 0, 0);
            f32x4 p1 = __builtin_amdgcn_mfma_f32_16x16x32_bf16(vr3[2].v, bf0, zero, 0, 0, 0);
            p1       = __builtin_amdgcn_mfma_f32_16x16x32_bf16(vr3[3].v, bf1, p1,   0, 0, 0);
            #pragma unroll
            for (int r = 0; r < 4; ++r) {
                oacc[6][r] = fmaf(coefB, p0[r], oacc[6][r]);
                oacc[7][r] = fmaf(coefB, p1[r], oacc[7][r]);
            }
        }
    }

    // ---- epilogue: 3-round LDS tree-combine (reuses qf region) ----
    __syncthreads();                       // qf reads done everywhere
    float* epi = (float*)(smem + kQOff);   // 4 slots x 2048 floats

    if (wave >= 4) {
        #pragma unroll
        for (int dt = 0; dt < 8; ++dt)
            *(f32x4*)&epi[(wave - 4) * 2048 + dt * 256 + lane * 4] = oacc[dt];
    }
    __syncthreads();
    if (wave < 4) {
        #pragma unroll
        for (int dt = 0; dt < 8; ++dt) {
            const f32x4 o = *(const f32x4*)&epi[wave * 2048 + dt * 256 + lane * 4];
            #pragma unroll
            for (int r = 0; r < 4; ++r) oacc[dt][r] += o[r];
        }
    }
    __syncthreads();
    if (wave == 2 || wave == 3) {
        #pragma unroll
        for (int dt = 0; dt < 8; ++dt)
            *(f32x4*)&epi[(wave - 2) * 2048 + dt * 256 + lane * 4] = oacc[dt];
    }
    __syncthreads();
    if (wave < 2) {
        #pragma unroll
        for (int dt = 0; dt < 8; ++dt) {
            const f32x4 o = *(const f32x4*)&epi[wave * 2048 + dt * 256 + lane * 4];
            #pragma unroll
            for (int r = 0; r < 4; ++r) oacc[dt][r] += o[r];
        }
    }
    __syncthreads();
    if (wave == 1) {
        #pragma unroll
        for (int dt = 0; dt < 8; ++dt)
            *(f32x4*)&epi[dt * 256 + lane * 4] = oacc[dt];
    }
    __syncthreads();
    if (wave == 0) {
        float* ob = out + ((size_t)l * kHQ + h * kG + n) * kD;
        #pragma unroll
        for (int dt = 0; dt < 8; ++dt) {
            const f32x4 o = *(const f32x4*)&epi[dt * 256 + lane * 4];
            float4 val;
            #pragma unroll
            for (int r = 0; r < 4; ++r) (&val.x)[r] = oacc[dt][r] + o[r];
            *(float4*)(ob + dt * 16 + quad * 4) = val;
        }
    }
}

} // namespace

extern "C" void kernel_launch(void* const* d_in, const int* in_sizes, int n_in,
                              void* d_out, int out_size, void* d_ws, size_t ws_size,
                              hipStream_t stream)
{
    const float* q    = (const float*)d_in[0];
    const float* k    = (const float*)d_in[1];
    const float* v    = (const float*)d_in[2];
    const float* w    = (const float*)d_in[3];
    const int*   bidx = (const int*)d_in[4];
    float* out = (float*)d_out;

    uint4* kp = (uint4*)d_ws;                                   // 2 MB
    uint4* vp = (uint4*)((char*)d_ws + (size_t)kKPackN * 16);   // 2 MB

    pack_kv<<<dim3(512), dim3(256), 0, stream>>>(k, v, kp, vp);
    hsa_main<<<dim3(kLq * kH), dim3(512), 0, stream>>>(q, w, bidx, kp, vp, out);
}

// Round 9
// 88.513 us; speedup vs baseline: 1.6351x; 1.0767x over previous
//
#include <hip/hip_runtime.h>
#include <hip/hip_bf16.h>

// HSA prefill R22 (resubmit; R8 bench was a GPU-broker timeout, no data).
// R22 = R17 body + L2-warm attack on first-touch latency.
// R21 post-mortem (95.3us): 24-in-flight prologue overflowed the 128-VGPR
// cap -> spill/serialize (3rd instance of this failure mode). Register-
// funded pipeline depth is tapped out at R17's 16-in-flight = 88.8us.
// Theory: the harness's 256MiB poison fill floods L2+L3 every iter;
// pack rewrites kp/vp but its dirty lines are flushed/scattered across all
// 8 XCDs -> hsa_main's KV reads are FIRST-TOUCH L3 latency (~700-900cy),
// while R17's refill distances (~150-300cy) only cover L2 (~200cy).
// Fix latency, not distance:
//   (1) XCD-h swizzle (R18 mapping, validated): per-XCD KV hot set = 2MB.
//   (2) cooperative L2 warm: each block fire-and-forgets 4 uint4 loads/thr
//       covering its 32KB slice of the XCD's 2MB -> whole set pulled into
//       local L2 in ~1us (BW-limited, overlapped with prologue); all
//       refills become ~200cy L2 hits, which R17's distances DO cover.
//       Loads kept live via end-of-kernel asm volatile (DCE guard).
//       [audit note: warmacc XOR forces an early waitcnt on the warm loads
//        — known imperfection, first suspect if result is neutral/negative]
//   (3) pack swizzle: pack blocks for head h run on the XCD half that
//       reads them -> lines may survive in the right L2 (warm partly free).
// Everything else R17 verbatim (16-in-flight streams, interleaved scores,
// qf in LDS, dual P slices, barrier-free loop, tree-combine epilogue).

namespace {

constexpr int kLq = 256, kHQ = 32, kH = 2, kG = 16, kD = 128, kS = 16;
constexpr int kNB = 64;                    // Lkv/BS: distinct blocks per head
constexpr float kScaleLog2e = 0.08838834764831845f * 1.4426950408889634f;

constexpr int kKPackN = kH * kNB * 16 * 64;  // uint4 elems per array (2 MB)
constexpr int kPStr   = 72;                  // P row stride (shorts)
constexpr int kSStr   = 136;                 // pack LDS row stride (shorts)

// main-kernel LDS layout (bytes):
//   [0, 32768)        qf slices:  wave*4096 + st*1024 + lane*16   (epilogue reuse)
//   [32768, 69632)    P slices:   wave*4608 + blk*2304 + (n*72+u)*2
constexpr int kQOff = 0;
constexpr int kPOff = 32768;

typedef short s16x8 __attribute__((ext_vector_type(8)));
typedef float f32x4 __attribute__((ext_vector_type(4)));

union U32BF2 { unsigned int u; __hip_bfloat162 h; };
union FragU  { uint4 u; s16x8 v; };

static __device__ inline unsigned int pk_bf16(float a, float b) {
    U32BF2 z; z.h = __float22bfloat162_rn(make_float2(a, b));
    return z.u;
}

// ---------------- pack kernel (R17 body; XCD-h-aligned work mapping) -------
// K_packed idx = ((h*64+blk)*16 + t*4+st)*64 + lane (lane = quad*16+n)
//   holds K[u = blk*64 + t*16 + n][h][d = st*32 + quad*8 + j]
// V_packed idx = ((h*64+blk)*16 + dt*2+st)*64 + lane
//   holds V[u = blk*64 + st*32 + quad*8 + j][h][d = dt*16 + n]
__global__ __launch_bounds__(256)
void pack_kv(const float* __restrict__ k, const float* __restrict__ v,
             uint4* __restrict__ kp, uint4* __restrict__ vp)
{
    __shared__ unsigned short S_s[32 * kSStr];   // 8.7 KB bf16 [u_loc][d]

    const int bid  = blockIdx.x;                 // 0..511
    // XCD-aligned mapping: xcd = bid&7 (dispatch round-robin); h = xcd>>2
    // so head h's pack blocks run on the XCD half that later reads them.
    const int xcd  = bid & 7;
    const int h    = xcd >> 2;
    const int idx  = (bid >> 3) * 4 + (xcd & 3); // 0..255, bijective
    const int isV  = idx & 1;
    const int half = (idx >> 1) & 1;
    const int blk  = idx >> 2;                   // 0..63
    const int t    = threadIdx.x;
    const int lane = t & 63, n = lane & 15, quad = lane >> 4;
    const int wv   = t >> 6;                     // 0..3

    {   // coalesced load 32 rows x 128 fp32 -> bf16 LDS
        const float* src = (isV ? v : k) +
            ((size_t)(blk * 64 + half * 32) * kH + h) * kD;
        const int r0 = t >> 5, c4 = (t & 31) << 2;
        #pragma unroll
        for (int p = 0; p < 4; ++p) {
            const int r = p * 8 + r0;
            const float4 f = *(const float4*)(src + (size_t)r * (kH * kD) + c4);
            *(unsigned int*)&S_s[r * kSStr + c4]     = pk_bf16(f.x, f.y);
            *(unsigned int*)&S_s[r * kSStr + c4 + 2] = pk_bf16(f.z, f.w);
        }
    }
    __syncthreads();

    const size_t obase = (size_t)(h * 64 + blk) * 16 * 64;
    if (!isV) {
        #pragma unroll
        for (int rep = 0; rep < 2; ++rep) {
            const int cl    = wv * 2 + rep;      // 0..7
            const int t_loc = cl >> 2, st = cl & 3;
            const int c     = (2 * half + t_loc) * 4 + st;
            const int u_loc = t_loc * 16 + n;
            kp[obase + (size_t)c * 64 + lane] =
                *(const uint4*)&S_s[u_loc * kSStr + st * 32 + quad * 8];
        }
    } else {
        #pragma unroll
        for (int rep = 0; rep < 2; ++rep) {
            const int dt = wv * 2 + rep;         // 0..7
            const int c  = dt * 2 + half;
            const int d  = dt * 16 + n;
            unsigned short s[8];
            #pragma unroll
            for (int j = 0; j < 8; ++j) s[j] = S_s[(quad * 8 + j) * kSStr + d];
            uint4 val;
            val.x = s[0] | ((unsigned)s[1] << 16);
            val.y = s[2] | ((unsigned)s[3] << 16);
            val.z = s[4] | ((unsigned)s[5] << 16);
            val.w = s[6] | ((unsigned)s[7] << 16);
            vp[obase + (size_t)c * 64 + lane] = val;
        }
    }
}

// ---------------- main kernel --------------------------------------------
__global__ __launch_bounds__(512, 4)
void hsa_main(const float* __restrict__ q, const float* __restrict__ w,
              const int* __restrict__ bidx, const uint4* __restrict__ kp,
              const uint4* __restrict__ vp, float* __restrict__ out)
{
    __shared__ __align__(16) unsigned char smem[69632];   // 68 KB (see layout)

    const int bid  = blockIdx.x;                 // 0..511
    // XCD-h swizzle: XCDs 0-3 handle h=0, XCDs 4-7 handle h=1 ->
    // per-XCD KV hot set is one head's kp+vp = 2 MB (< 4 MB L2).
    const int xcd  = bid & 7;
    const int h    = xcd >> 2;
    const int l    = (bid >> 3) * 4 + (xcd & 3);
    const int tid  = threadIdx.x;
    const int wave = tid >> 6;                   // 0..7
    const int lane = tid & 63;
    const int n    = lane & 15;
    const int quad = lane >> 4;

    // ---- L2 warm: fire-and-forget this block's 32 KB slice of the XCD's
    //      2 MB KV set (64 blocks/XCD cover it all in parallel). No one
    //      waits on these; the end-of-kernel asm keeps them un-DCE'd. ----
    unsigned warmacc;
    {
        const int widx = bid >> 3;               // 0..63: slice within XCD
        const uint4* kph = kp + (size_t)h * 65536 + (size_t)widx * 1024;
        const uint4* vph = vp + (size_t)h * 65536 + (size_t)widx * 1024;
        const uint4 a0 = kph[tid];
        const uint4 a1 = kph[512 + tid];
        const uint4 b0 = vph[tid];
        const uint4 b1 = vph[512 + tid];
        warmacc = a0.x ^ a1.x ^ b0.x ^ b1.x;
    }
    __builtin_amdgcn_sched_barrier(0);           // pin warm issue first

    // ---- Q B-frags -> per-wave LDS slice (frees 16 VGPR) ----
    unsigned char* qlds = smem + kQOff + wave * 4096 + lane * 16;
    {
        const float* qb = q + ((size_t)l * kHQ + h * kG + n) * kD + quad * 8;
        #pragma unroll
        for (int st = 0; st < 4; ++st) {
            const float4 f0 = *(const float4*)(qb + st * 32);
            const float4 f1 = *(const float4*)(qb + st * 32 + 4);
            uint4 z;
            z.x = pk_bf16(f0.x, f0.y); z.y = pk_bf16(f0.z, f0.w);
            z.z = pk_bf16(f1.x, f1.y); z.w = pk_bf16(f1.z, f1.w);
            *(uint4*)(qlds + st * 1024) = z;
        }
    }

    // this wave's 2 s-blocks A,B: s = wave*2 + {0,1}
    int   baseA, baseB;
    float wvalA, wvalB;
    {
        const int sA = wave * 2, sB = wave * 2 + 1;
        const int biA = bidx[(size_t)(l * kH + h) * kS + sA];
        const int biB = bidx[(size_t)(l * kH + h) * kS + sB];
        wvalA = (biA < 0) ? 0.f : w[((size_t)l * kHQ + h * kG + n) * kS + sA];
        wvalB = (biB < 0) ? 0.f : w[((size_t)l * kHQ + h * kG + n) * kS + sB];
        baseA = (h * kNB + max(biA, 0)) * 1024;
        baseB = (h * kNB + max(biB, 0)) * 1024;
    }

    unsigned short* PA = (unsigned short*)(smem + kPOff + wave * 4608);
    unsigned short* PB = PA + kG * kPStr;

    // prologue: kA <- A-K-g0, kB <- B-K-g0, vrA <- A-V-g0, vrB <- A-V-g1
    // (16 loads in flight; vr banks drain under the scores phase)
    FragU kA[4], kB[4], vrA[4], vrB[4];
    #pragma unroll
    for (int st = 0; st < 4; ++st) kA[st].u = kp[baseA + st * 64 + lane];
    #pragma unroll
    for (int st = 0; st < 4; ++st) kB[st].u = kp[baseB + st * 64 + lane];
    #pragma unroll
    for (int i = 0; i < 4; ++i)    vrA[i].u = vp[baseA + i * 64 + lane];
    #pragma unroll
    for (int i = 0; i < 4; ++i)    vrB[i].u = vp[baseA + (4 + i) * 64 + lane];
    __builtin_amdgcn_sched_barrier(0);

    f32x4 oacc[8];
    #pragma unroll
    for (int dt = 0; dt < 8; ++dt) oacc[dt] = (f32x4){0.f, 0.f, 0.f, 0.f};

    // ---- interleaved scores: A-t, B-t alternate (refill distance ~1 group) ----
    float partA = 0.f, partB = 0.f;
    #pragma unroll
    for (int t = 0; t < 4; ++t) {
        {   // A group t
            f32x4 sc = {0.f, 0.f, 0.f, 0.f};
            #pragma unroll
            for (int st = 0; st < 4; ++st) {
                const s16x8 aq = *(const s16x8*)(qlds + st * 1024);
                sc = __builtin_amdgcn_mfma_f32_16x16x32_bf16(kA[st].v, aq, sc, 0, 0, 0);
            }
            if (t < 3) {
                #pragma unroll
                for (int st = 0; st < 4; ++st)
                    kA[st].u = kp[baseA + ((t + 1) * 4 + st) * 64 + lane];
            }
            __builtin_amdgcn_sched_barrier(0);
            #pragma unroll
            for (int r = 0; r < 4; ++r) {
                sc[r] = exp2f(sc[r] * kScaleLog2e);
                partA += sc[r];
            }
            const unsigned long long pq =
                ((unsigned long long)pk_bf16(sc[2], sc[3]) << 32) | pk_bf16(sc[0], sc[1]);
            *(unsigned long long*)&PA[n * kPStr + t * 16 + quad * 4] = pq;
        }
        {   // B group t
            f32x4 sc = {0.f, 0.f, 0.f, 0.f};
            #pragma unroll
            for (int st = 0; st < 4; ++st) {
                const s16x8 aq = *(const s16x8*)(qlds + st * 1024);
                sc = __builtin_amdgcn_mfma_f32_16x16x32_bf16(kB[st].v, aq, sc, 0, 0, 0);
            }
            if (t < 3) {
                #pragma unroll
                for (int st = 0; st < 4; ++st)
                    kB[st].u = kp[baseB + ((t + 1) * 4 + st) * 64 + lane];
            }
            __builtin_amdgcn_sched_barrier(0);
            #pragma unroll
            for (int r = 0; r < 4; ++r) {
                sc[r] = exp2f(sc[r] * kScaleLog2e);
                partB += sc[r];
            }
            const unsigned long long pq =
                ((unsigned long long)pk_bf16(sc[2], sc[3]) << 32) | pk_bf16(sc[0], sc[1]);
            *(unsigned long long*)&PB[n * kPStr + t * 16 + quad * 4] = pq;
        }
    }

    // ---- intra-wave denominators ----
    partA += __shfl_xor(partA, 16);
    partA += __shfl_xor(partA, 32);
    partB += __shfl_xor(partB, 16);
    partB += __shfl_xor(partB, 32);
    const float coefA = wvalA / partA;
    const float coefB = wvalB / partB;

    const f32x4 zero = {0.f, 0.f, 0.f, 0.f};

    // ---- PV(A): banks alternate; refill distance = 2 V-groups ----
    {
        const s16x8 bf0 = *(const s16x8*)&PA[n * kPStr + quad * 8];
        const s16x8 bf1 = *(const s16x8*)&PA[n * kPStr + 32 + quad * 8];

        // vg0: vrA = A-g0 -> d-tiles 0,1 ; refill vrA <- A-g2
        {
            f32x4 p0 = __builtin_amdgcn_mfma_f32_16x16x32_bf16(vrA[0].v, bf0, zero, 0, 0, 0);
            p0       = __builtin_amdgcn_mfma_f32_16x16x32_bf16(vrA[1].v, bf1, p0,   0, 0, 0);
            f32x4 p1 = __builtin_amdgcn_mfma_f32_16x16x32_bf16(vrA[2].v, bf0, zero, 0, 0, 0);
            p1       = __builtin_amdgcn_mfma_f32_16x16x32_bf16(vrA[3].v, bf1, p1,   0, 0, 0);
            #pragma unroll
            for (int i = 0; i < 4; ++i) vrA[i].u = vp[baseA + (8 + i) * 64 + lane];
            __builtin_amdgcn_sched_barrier(0);
            #pragma unroll
            for (int r = 0; r < 4; ++r) {
                oacc[0][r] = fmaf(coefA, p0[r], oacc[0][r]);
                oacc[1][r] = fmaf(coefA, p1[r], oacc[1][r]);
            }
        }
        // vg1: vrB = A-g1 -> d-tiles 2,3 ; refill vrB <- A-g3
        {
            f32x4 p0 = __builtin_amdgcn_mfma_f32_16x16x32_bf16(vrB[0].v, bf0, zero, 0, 0, 0);
            p0       = __builtin_amdgcn_mfma_f32_16x16x32_bf16(vrB[1].v, bf1, p0,   0, 0, 0);
            f32x4 p1 = __builtin_amdgcn_mfma_f32_16x16x32_bf16(vrB[2].v, bf0, zero, 0, 0, 0);
            p1       = __builtin_amdgcn_mfma_f32_16x16x32_bf16(vrB[3].v, bf1, p1,   0, 0, 0);
            #pragma unroll
            for (int i = 0; i < 4; ++i) vrB[i].u = vp[baseA + (12 + i) * 64 + lane];
            __builtin_amdgcn_sched_barrier(0);
            #pragma unroll
            for (int r = 0; r < 4; ++r) {
                oacc[2][r] = fmaf(coefA, p0[r], oacc[2][r]);
                oacc[3][r] = fmaf(coefA, p1[r], oacc[3][r]);
            }
        }
        // vg2: vrA = A-g2 -> d-tiles 4,5 ; refill vrA <- B-g0
        {
            f32x4 p0 = __builtin_amdgcn_mfma_f32_16x16x32_bf16(vrA[0].v, bf0, zero, 0, 0, 0);
            p0       = __builtin_amdgcn_mfma_f32_16x16x32_bf16(vrA[1].v, bf1, p0,   0, 0, 0);
            f32x4 p1 = __builtin_amdgcn_mfma_f32_16x16x32_bf16(vrA[2].v, bf0, zero, 0, 0, 0);
            p1       = __builtin_amdgcn_mfma_f32_16x16x32_bf16(vrA[3].v, bf1, p1,   0, 0, 0);
            #pragma unroll
            for (int i = 0; i < 4; ++i) vrA[i].u = vp[baseB + i * 64 + lane];
            __builtin_amdgcn_sched_barrier(0);
            #pragma unroll
            for (int r = 0; r < 4; ++r) {
                oacc[4][r] = fmaf(coefA, p0[r], oacc[4][r]);
                oacc[5][r] = fmaf(coefA, p1[r], oacc[5][r]);
            }
        }
        // vg3: vrB = A-g3 -> d-tiles 6,7 ; refill vrB <- B-g1
        {
            f32x4 p0 = __builtin_amdgcn_mfma_f32_16x16x32_bf16(vrB[0].v, bf0, zero, 0, 0, 0);
            p0       = __builtin_amdgcn_mfma_f32_16x16x32_bf16(vrB[1].v, bf1, p0,   0, 0, 0);
            f32x4 p1 = __builtin_amdgcn_mfma_f32_16x16x32_bf16(vrB[2].v, bf0, zero, 0, 0, 0);
            p1       = __builtin_amdgcn_mfma_f32_16x16x32_bf16(vrB[3].v, bf1, p1,   0, 0, 0);
            #pragma unroll
            for (int i = 0; i < 4; ++i) vrB[i].u = vp[baseB + (4 + i) * 64 + lane];
            __builtin_amdgcn_sched_barrier(0);
            #pragma unroll
            for (int r = 0; r < 4; ++r) {
                oacc[6][r] = fmaf(coefA, p0[r], oacc[6][r]);
                oacc[7][r] = fmaf(coefA, p1[r], oacc[7][r]);
            }
        }
    }

    // ---- PV(B): same bank rotation on block B ----
    {
        const s16x8 bf0 = *(const s16x8*)&PB[n * kPStr + quad * 8];
        const s16x8 bf1 = *(const s16x8*)&PB[n * kPStr + 32 + quad * 8];

        // vg0: vrA = B-g0 -> d-tiles 0,1 ; refill vrA <- B-g2
        {
            f32x4 p0 = __builtin_amdgcn_mfma_f32_16x16x32_bf16(vrA[0].v, bf0, zero, 0, 0, 0);
            p0       = __builtin_amdgcn_mfma_f32_16x16x32_bf16(vrA[1].v, bf1, p0,   0, 0, 0);
            f32x4 p1 = __builtin_amdgcn_mfma_f32_16x16x32_bf16(vrA[2].v, bf0, zero, 0, 0, 0);
            p1       = __builtin_amdgcn_mfma_f32_16x16x32_bf16(vrA[3].v, bf1, p1,   0, 0, 0);
            #pragma unroll
            for (int i = 0; i < 4; ++i) vrA[i].u = vp[baseB + (8 + i) * 64 + lane];
            __builtin_amdgcn_sched_barrier(0);
            #pragma unroll
            for (int r = 0; r < 4; ++r) {
                oacc[0][r] = fmaf(coefB, p0[r], oacc[0][r]);
                oacc[1][r] = fmaf(coefB, p1[r], oacc[1][r]);
            }
        }
        // vg1: vrB = B-g1 -> d-tiles 2,3 ; refill vrB <- B-g3
        {
            f32x4 p0 = __builtin_amdgcn_mfma_f32_16x16x32_bf16(vrB[0].v, bf0, zero, 0, 0, 0);
            p0       = __builtin_amdgcn_mfma_f32_16x16x32_bf16(vrB[1].v, bf1, p0,   0, 0, 0);
            f32x4 p1 = __builtin_amdgcn_mfma_f32_16x16x32_bf16(vrB[2].v, bf0, zero, 0, 0, 0);
            p1       = __builtin_amdgcn_mfma_f32_16x16x32_bf16(vrB[3].v, bf1, p1,   0, 0, 0);
            #pragma unroll
            for (int i = 0; i < 4; ++i) vrB[i].u = vp[baseB + (12 + i) * 64 + lane];
            __builtin_amdgcn_sched_barrier(0);
            #pragma unroll
            for (int r = 0; r < 4; ++r) {
                oacc[2][r] = fmaf(coefB, p0[r], oacc[2][r]);
                oacc[3][r] = fmaf(coefB, p1[r], oacc[3][r]);
            }
        }
        // vg2: vrA = B-g2 -> d-tiles 4,5 (no refill)
        {
            f32x4 p0 = __builtin_amdgcn_mfma_f32_16x16x32_bf16(vrA[0].v, bf0, zero, 0, 0, 0);
            p0       = __builtin_amdgcn_mfma_f32_16x16x32_bf16(vrA[1].v, bf1, p0,   0, 0, 0);
            f32x4 p1 = __builtin_amdgcn_mfma_f32_16x16x32_bf16(vrA[2].v, bf0, zero, 0, 0, 0);
            p1       = __builtin_amdgcn_mfma_f32_16x16x32_bf16(vrA[3].v, bf1, p1,   0, 0, 0);
            #pragma unroll
            for (int r = 0; r < 4; ++r) {
                oacc[4][r] = fmaf(coefB, p0[r], oacc[4][r]);
                oacc[5][r] = fmaf(coefB, p1[r], oacc[5][r]);
            }
        }
        // vg3: vrB = B-g3 -> d-tiles 6,7 (no refill)
        {
            f32x4 p0 = __builtin_amdgcn_mfma_f32_16x16x32_bf16(vrB[0].v, bf0, zero, 0, 0, 0);
            p0       = __builtin_amdgcn_mfma_f32_16x16x32_bf16(vrB[1].v, bf1, p0,   0, 0, 0);
            f32x4 p1 = __builtin_amdgcn_mfma_f32_16x16x32_bf16(vrB[2].v, bf0, zero, 0, 0, 0);
            p1       = __builtin_amdgcn_mfma_f32_16x16x32_bf16(vrB[3].v, bf1, p1,   0, 0, 0);
            #pragma unroll
            for (int r = 0; r < 4; ++r) {
                oacc[6][r] = fmaf(coefB, p0[r], oacc[6][r]);
                oacc[7][r] = fmaf(coefB, p1[r], oacc[7][r]);
            }
        }
    }

    // ---- epilogue: 3-round LDS tree-combine (reuses qf region) ----
    __syncthreads();                       // qf reads done everywhere
    float* epi = (float*)(smem + kQOff);   // 4 slots x 2048 floats

    if (wave >= 4) {
        #pragma unroll
        for (int dt = 0; dt < 8; ++dt)
            *(f32x4*)&epi[(wave - 4) * 2048 + dt * 256 + lane * 4] = oacc[dt];
    }
    __syncthreads();
    if (wave < 4) {
        #pragma unroll
        for (int dt = 0; dt < 8; ++dt) {
            const f32x4 o = *(const f32x4*)&epi[wave * 2048 + dt * 256 + lane * 4];
            #pragma unroll
            for (int r = 0; r < 4; ++r) oacc[dt][r] += o[r];
        }
    }
    __syncthreads();
    if (wave == 2 || wave == 3) {
        #pragma unroll
        for (int dt = 0; dt < 8; ++dt)
            *(f32x4*)&epi[(wave - 2) * 2048 + dt * 256 + lane * 4] = oacc[dt];
    }
    __syncthreads();
    if (wave < 2) {
        #pragma unroll
        for (int dt = 0; dt < 8; ++dt) {
            const f32x4 o = *(const f32x4*)&epi[wave * 2048 + dt * 256 + lane * 4];
            #pragma unroll
            for (int r = 0; r < 4; ++r) oacc[dt][r] += o[r];
        }
    }
    __syncthreads();
    if (wave == 1) {
        #pragma unroll
        for (int dt = 0; dt < 8; ++dt)
            *(f32x4*)&epi[dt * 256 + lane * 4] = oacc[dt];
    }
    __syncthreads();
    if (wave == 0) {
        float* ob = out + ((size_t)l * kHQ + h * kG + n) * kD;
        #pragma unroll
        for (int dt = 0; dt < 8; ++dt) {
            const f32x4 o = *(const f32x4*)&epi[dt * 256 + lane * 4];
            float4 val;
            #pragma unroll
            for (int r = 0; r < 4; ++r) (&val.x)[r] = oacc[dt][r] + o[r];
            *(float4*)(ob + dt * 16 + quad * 4) = val;
        }
    }

    // keep the warm loads alive (no-op, 1 VGPR)
    asm volatile("" :: "v"(warmacc));
}

} // namespace

extern "C" void kernel_launch(void* const* d_in, const int* in_sizes, int n_in,
                              void* d_out, int out_size, void* d_ws, size_t ws_size,
                              hipStream_t stream)
{
    const float* q    = (const float*)d_in[0];
    const float* k    = (const float*)d_in[1];
    const float* v    = (const float*)d_in[2];
    const float* w    = (const float*)d_in[3];
    const int*   bidx = (const int*)d_in[4];
    float* out = (float*)d_out;

    uint4* kp = (uint4*)d_ws;                                   // 2 MB
    uint4* vp = (uint4*)((char*)d_ws + (size_t)kKPackN * 16);   // 2 MB

    pack_kv<<<dim3(512), dim3(256), 0, stream>>>(k, v, kp, vp);
    hsa_main<<<dim3(kLq * kH), dim3(512), 0, stream>>>(q, w, bidx, kp, vp, out);
}